// Round 4
// baseline (356.063 us; speedup 1.0000x reference)
//
#include <hip/hip_runtime.h>
#include <hip/hip_bf16.h>
#include <stdint.h>

// ---------------------------------------------------------------------------
// wannModel: x0 = x@Ws^T + bs;  h_{l+1} = relu(h_l@W_l^T + b_l) + x0 (32x);
//            out = softmax(h@Wo^T + bo)  over 64 classes.
//
// Transposed-orientation MFMA chain (out^T = W * h^T). k-index mismatch
// absorbed by pre-permuting weights' k axis (pi) in a prep kernel. h stays
// in registers across all 32 layers (mt=2: 32 rows/wave).
//
// R9 post-mortem: counted-vmcnt pipeline landed clean (no spill) but only
// -7%: Occupancy 26.9% decomposes as 42% of wall time in the 256-block
// dispatch tail at 1 block/CU (grid 1024 over 768 resident slots). Tail
// processes 25% of work in 42% of time.
// R10: tail-free geometry at mt=2: 512-thread blocks (8 waves x 32 rows),
// grid 512 == exactly 2 blocks/CU (one dispatch round, zero tail), 16
// waves/CU resident. launch_bounds(512,4) -> joint budget 128; demand cut
// to ~125-135 via ntl-outer passes (acc[2] not [2][2], bias 1 F4 at a
// time). Stage = 3 global_load_lds/wave (2x16B weights + 1 bias) ->
// vmcnt(3) counted waits, same triple-buffer 2-ahead pipeline as R9.
// ---------------------------------------------------------------------------

typedef short bs8 __attribute__((ext_vector_type(8)));   // 8 x bf16 bits
typedef float f32x4 __attribute__((ext_vector_type(4)));

union Frag { bs8 v; uint32_t u[4]; };
union F4   { float4 f; f32x4 v; };

__device__ __forceinline__ uint32_t cvtpk(float lo, float hi) {
#if __has_builtin(__builtin_amdgcn_cvt_pk_bf16_f32)
  auto r = __builtin_amdgcn_cvt_pk_bf16_f32(lo, hi);   // dst.lo=cvt(lo)
  uint32_t u; __builtin_memcpy(&u, &r, 4);
  return u;
#else
  union { float f; uint32_t u; } a, b; a.f = lo; b.f = hi;
  uint32_t ra = a.u + 0x7fffu + ((a.u >> 16) & 1u);    // RNE, no NaN check
  uint32_t rb = b.u + 0x7fffu + ((b.u >> 16) & 1u);
  return (ra >> 16) | (rb & 0xffff0000u);
#endif
}

// ---------------------------------------------------------------------------
// Preprocess. Chunk layout in d_ws (uint16 units, 8320 elems = 16640 B each):
//   chunk c base = c*8320.  [0,8192) = weight frags (4 ntloc x 4 kt),
//   [8192,8320) = 256 B bias (64 floats for this half-layer).
// Chunks: 0,1 = W_start halves (NATURAL k) + b_start halves;
//         2+2l+h = layer l half h (PI-permuted k) + layer_b[l] half h;
//         66 = W_out (4 nt, PI-permuted) + b_out (64 floats).
// Weight element in chunk: ((ntloc*4+kt)*64 + lane)*8 + j.
// ---------------------------------------------------------------------------
__global__ void prep_frags(const float* __restrict__ w_start,
                           const float* __restrict__ b_start,
                           const float* __restrict__ masked_w,
                           const float* __restrict__ layer_b,
                           const float* __restrict__ w_out,
                           const float* __restrict__ b_out,
                           uint16_t* __restrict__ dst) {
  int t = blockIdx.x * 256 + threadIdx.x;
  if (t >= 69680) return;
  if (t >= 68608) {                            // bias floats, 4 per thread
    int f = (t - 68608) * 4;
    int c, off; const float* src;
    if (f < 128)       { c = f >> 6;               off = f & 63; src = b_start + f; }
    else if (f < 4224) { int g = f - 128;  c = 2 + (g >> 6); off = g & 63; src = layer_b + g; }
    else               { int g = f - 4224; c = 66;           off = g;      src = b_out + g; }
    float4 v = *reinterpret_cast<const float4*>(src);
    *reinterpret_cast<float4*>(
        reinterpret_cast<float*>(dst + (size_t)c * 8320 + 8192) + off) = v;
    return;
  }
  int lane = t & 63, kt = (t >> 6) & 3, q = lane >> 4, m15 = lane & 15;
  float f[8];
  int c, ntloc;
  if (t < 2048) {                              // W_start (natural k)
    int nt = (t >> 8) & 7;
    c = nt >> 2; ntloc = nt & 3;
    const float* s = w_start + (nt * 16 + m15) * 128 + q * 8 + kt * 32;
    #pragma unroll
    for (int j = 0; j < 8; ++j) f[j] = s[j];
  } else if (t < 67584) {                      // chain (pi-permuted k)
    int t2 = t - 2048, l = t2 >> 11, nt = (t2 >> 8) & 7;
    c = 2 + 2 * l + (nt >> 2); ntloc = nt & 3;
    const float* s = masked_w + ((l * 128) + nt * 16 + m15) * 128 + q * 4 + kt * 32;
    #pragma unroll
    for (int j = 0; j < 8; ++j) f[j] = s[(j & 3) + 16 * (j >> 2)];
  } else {                                     // W_out (pi-permuted k)
    int t3 = t - 67584, nt = (t3 >> 8) & 3;
    c = 66; ntloc = nt;
    const float* s = w_out + (nt * 16 + m15) * 128 + q * 4 + kt * 32;
    #pragma unroll
    for (int j = 0; j < 8; ++j) f[j] = s[(j & 3) + 16 * (j >> 2)];
  }
  uint4 o;
  o.x = cvtpk(f[0], f[1]); o.y = cvtpk(f[2], f[3]);
  o.z = cvtpk(f[4], f[5]); o.w = cvtpk(f[6], f[7]);
  *reinterpret_cast<uint4*>(dst + (size_t)c * 8320 +
                            ((ntloc * 4 + kt) * 64 + lane) * 8) = o;
}

// ---------------------------------------------------------------------------
// Main kernel: 512 blocks x 512 threads (8 waves; wave owns 32 batch cols
// = 2 m-tiles of 16; block owns 256 rows). LDS 49920B = 3 chunk slots.
// Phase(c): s_waitcnt vmcnt(3) -> s_barrier -> stage chunk c+2 -> compute c.
// Exactly 2 blocks/CU resident; grid == one dispatch round, no tail.
// ---------------------------------------------------------------------------
extern __shared__ uint16_t lds[];

#define VMW(N) asm volatile("s_waitcnt vmcnt(" #N ")" ::: "memory")

__global__ void __launch_bounds__(512, 4)
wann_main(const float* __restrict__ x,
          const uint16_t* __restrict__ wfrag,
          float* __restrict__ out) {
  const int tid  = threadIdx.x;
  const int lane = tid & 63;
  const int wave = tid >> 6;
  const int q    = lane >> 4;
  const int mc   = lane & 15;
  const long batch0 = (long)blockIdx.x * 256 + wave * 32;
  const f32x4 zero4 = {0.f, 0.f, 0.f, 0.f};

  auto slotp = [&](uint32_t s) -> uint16_t* { return lds + (size_t)s * 8320; };

  // stage one chunk: 2 x width-16 (weights) + 1 x width-4 (bias) per wave.
  // Exactly 3 vmcnt ops per stage -> counted waits are exact.
  auto stage = [&](uint16_t* dstb, uint32_t c) {
    const uint16_t* srcb = wfrag + (size_t)c * 8320;
    #pragma unroll
    for (int i = 0; i < 2; ++i) {
      __builtin_amdgcn_global_load_lds(
          (const __attribute__((address_space(1))) void*)(srcb + wave * 1024 + i * 512 + lane * 8),
          (__attribute__((address_space(3))) void*)(dstb + wave * 1024 + i * 512),
          16, 0, 0);
    }
    // bias: all 8 waves write the same 256B (same data; benign duplication)
    __builtin_amdgcn_global_load_lds(
        (const __attribute__((address_space(1))) void*)(srcb + 8192 + lane * 2),
        (__attribute__((address_space(3))) void*)(dstb + 8192),
        4, 0, 0);
  };

  auto barx = [&]() {
    asm volatile("" ::: "memory");
    __builtin_amdgcn_s_barrier();
    asm volatile("" ::: "memory");
  };

  // ---- load x fragments (natural k: B[k=8q+j+32kt][batch=mc]) ----
  Frag xf[2][4];
  #pragma unroll
  for (int mt = 0; mt < 2; ++mt) {
    const float* xrow = x + (batch0 + mt * 16 + mc) * 128 + q * 8;
    #pragma unroll
    for (int kt = 0; kt < 4; ++kt) {
      float4 a = *reinterpret_cast<const float4*>(xrow + kt * 32);
      float4 b = *reinterpret_cast<const float4*>(xrow + kt * 32 + 4);
      xf[mt][kt].u[0] = cvtpk(a.x, a.y);
      xf[mt][kt].u[1] = cvtpk(a.z, a.w);
      xf[mt][kt].u[2] = cvtpk(b.x, b.y);
      xf[mt][kt].u[3] = cvtpk(b.z, b.w);
    }
  }

  stage(slotp(0), 0);                        // W_start half 0
  stage(slotp(1), 1);                        // W_start half 1

  Frag x0f[2][4], hA[2][4], hB[2][4];

  // ---- start layer half h (ntl-outer: acc[2], one bias F4 live) ----
  auto start_half = [&](const uint16_t* buf, int h) {
    const float* bbb = reinterpret_cast<const float*>(buf + 8192);
    #pragma unroll
    for (int pp = 0; pp < 2; ++pp) {
      const int p = 2 * h + pp;
      #pragma unroll
      for (int ntl = 0; ntl < 2; ++ntl) {
        const int ntloc = 2 * pp + ntl;
        F4 bb;
        bb.f = *reinterpret_cast<const float4*>(bbb + ntloc * 16 + q * 4);
        f32x4 acc[2];
        __builtin_amdgcn_s_setprio(1);
        #pragma unroll
        for (int kt = 0; kt < 4; ++kt) {
          Frag wf;
          wf.v = *reinterpret_cast<const bs8*>(buf + ((ntloc * 4 + kt) * 64 + lane) * 8);
          #pragma unroll
          for (int mt = 0; mt < 2; ++mt) {
            f32x4 c = (kt == 0) ? bb.v : acc[mt];
            acc[mt] = __builtin_amdgcn_mfma_f32_16x16x32_bf16(wf.v, xf[mt][kt].v, c, 0, 0, 0);
          }
        }
        __builtin_amdgcn_s_setprio(0);
        #pragma unroll
        for (int mt = 0; mt < 2; ++mt) {
          x0f[mt][p].u[2 * ntl + 0] = cvtpk(acc[mt][0], acc[mt][1]);
          x0f[mt][p].u[2 * ntl + 1] = cvtpk(acc[mt][2], acc[mt][3]);
        }
      }
    }
  };

  // ---- chain layer half h: hout = bf16(relu(acc_with_bias) + x0) ----
  auto chain_half = [&](const uint16_t* buf, int h,
                        Frag (&hin)[2][4], Frag (&hout)[2][4]) {
    const float* bbb = reinterpret_cast<const float*>(buf + 8192);
    #pragma unroll
    for (int pp = 0; pp < 2; ++pp) {
      const int p = 2 * h + pp;
      #pragma unroll
      for (int ntl = 0; ntl < 2; ++ntl) {
        const int ntloc = 2 * pp + ntl;
        F4 bb;
        bb.f = *reinterpret_cast<const float4*>(bbb + ntloc * 16 + q * 4);
        f32x4 acc[2];
        __builtin_amdgcn_s_setprio(1);
        #pragma unroll
        for (int kt = 0; kt < 4; ++kt) {
          Frag wf;
          wf.v = *reinterpret_cast<const bs8*>(buf + ((ntloc * 4 + kt) * 64 + lane) * 8);
          #pragma unroll
          for (int mt = 0; mt < 2; ++mt) {
            f32x4 c = (kt == 0) ? bb.v : acc[mt];
            acc[mt] = __builtin_amdgcn_mfma_f32_16x16x32_bf16(wf.v, hin[mt][kt].v, c, 0, 0, 0);
          }
        }
        __builtin_amdgcn_s_setprio(0);
        #pragma unroll
        for (int mt = 0; mt < 2; ++mt) {
          f32x4 r = __builtin_elementwise_max(acc[mt], zero4);
          uint32_t xw0 = x0f[mt][p].u[2 * ntl + 0];
          uint32_t xw1 = x0f[mt][p].u[2 * ntl + 1];
          f32x4 xv;
          xv[0] = __uint_as_float(xw0 << 16);
          xv[1] = __uint_as_float(xw0 & 0xffff0000u);
          xv[2] = __uint_as_float(xw1 << 16);
          xv[3] = __uint_as_float(xw1 & 0xffff0000u);
          r = r + xv;
          hout[mt][p].u[2 * ntl + 0] = cvtpk(r[0], r[1]);
          hout[mt][p].u[2 * ntl + 1] = cvtpk(r[2], r[3]);
        }
      }
    }
  };

  // ---- start layer: phases for chunks 0,1 ----
  VMW(3); barx(); stage(slotp(2), 2);        // L0c0
  start_half(slotp(0), 0);
  VMW(3); barx(); stage(slotp(0), 3);        // L0c1
  start_half(slotp(1), 1);
  #pragma unroll
  for (int mt = 0; mt < 2; ++mt)
    #pragma unroll
    for (int kt = 0; kt < 4; ++kt)
      hA[mt][kt].v = x0f[mt][kt].v;          // h = x0

  // ---- 32 layers, 2 chunks each; slots rotate mod 3; stage 2 ahead ----
  uint32_t s0 = 2;                           // slot of chunk c0 = 2+2l
  #pragma unroll 1
  for (int l = 0; l < 32; l += 2) {
    const uint32_t s1 = (s0 + 1 < 3) ? s0 + 1 : 0;
    const uint32_t s2 = (s1 + 1 < 3) ? s1 + 1 : 0;
    const uint32_t c0 = 2 + 2 * (uint32_t)l;

    // layer l half 0 (chunk c0, slot s0); stage c0+2 -> s2
    VMW(3); barx(); stage(slotp(s2), c0 + 2);
    chain_half(slotp(s0), 0, hA, hB);
    // layer l half 1 (chunk c0+1, slot s1); stage c0+3 -> s0
    VMW(3); barx(); stage(slotp(s0), c0 + 3);
    chain_half(slotp(s1), 1, hA, hB);
    // layer l+1 half 0 (chunk c0+2, slot s2); stage c0+4 -> s1
    VMW(3); barx(); if (c0 + 4 <= 66) stage(slotp(s1), c0 + 4);
    chain_half(slotp(s2), 0, hB, hA);
    // layer l+1 half 1 (chunk c0+3, slot s0); stage c0+5 -> s2
    VMW(3); barx(); if (c0 + 5 <= 66) stage(slotp(s2), c0 + 5);
    chain_half(slotp(s0), 1, hB, hA);

    s0 = s1;
  }

  // ---- output layer: chunk 66 (slot 0): W_out + b_out from LDS ----
  VMW(0); barx();
  const uint16_t* wo = slotp(0);
  const float* bob = reinterpret_cast<const float*>(wo + 8192);
  F4 bo[4];
  #pragma unroll
  for (int nt = 0; nt < 4; ++nt)
    bo[nt].f = *reinterpret_cast<const float4*>(bob + nt * 16 + q * 4);
  f32x4 ao[4][2];  // [nt][mt]
  __builtin_amdgcn_s_setprio(1);
  #pragma unroll
  for (int kt = 0; kt < 4; ++kt) {
    #pragma unroll
    for (int nt = 0; nt < 4; ++nt) {
      Frag wf;
      wf.v = *reinterpret_cast<const bs8*>(wo + ((nt * 4 + kt) * 64 + lane) * 8);
      #pragma unroll
      for (int mt = 0; mt < 2; ++mt) {
        f32x4 c = (kt == 0) ? bo[nt].v : ao[nt][mt];
        ao[nt][mt] = __builtin_amdgcn_mfma_f32_16x16x32_bf16(wf.v, hA[mt][kt].v, c, 0, 0, 0);
      }
    }
  }
  __builtin_amdgcn_s_setprio(0);

  // ---- softmax over 64 classes + transposed store via LDS scratch ----
  // All waves are done reading slot 0 (W_out) after this barrier; full LDS
  // becomes per-wave scratch (8 waves x 4352 B = 34816 B < 49920 B).
  barx();
  float* tr = reinterpret_cast<float*>(lds) + wave * 1088;   // 16x68 floats
  #pragma unroll
  for (int mt = 0; mt < 2; ++mt) {
    float e[16];
    float M = -3.0e38f;
    #pragma unroll
    for (int nt = 0; nt < 4; ++nt)
      #pragma unroll
      for (int r = 0; r < 4; ++r)
        M = fmaxf(M, ao[nt][mt][r]);
    M = fmaxf(M, __shfl_xor(M, 16, 64));
    M = fmaxf(M, __shfl_xor(M, 32, 64));
    float S = 0.0f;
    #pragma unroll
    for (int nt = 0; nt < 4; ++nt)
      #pragma unroll
      for (int r = 0; r < 4; ++r) {
        float t = exp2f((ao[nt][mt][r] - M) * 1.4426950408889634f);
        e[nt * 4 + r] = t;
        S += t;
      }
    S += __shfl_xor(S, 16, 64);
    S += __shfl_xor(S, 32, 64);
    const float inv = 1.0f / S;
    #pragma unroll
    for (int nt = 0; nt < 4; ++nt) {
      float4 pv;
      pv.x = e[nt * 4 + 0] * inv;
      pv.y = e[nt * 4 + 1] * inv;
      pv.z = e[nt * 4 + 2] * inv;
      pv.w = e[nt * 4 + 3] * inv;
      *reinterpret_cast<float4*>(tr + mc * 68 + nt * 16 + q * 4) = pv;
    }
    __asm__ volatile("s_waitcnt lgkmcnt(0)" ::: "memory");
    #pragma unroll
    for (int it = 0; it < 4; ++it) {
      int row = it * 4 + (lane >> 4);
      float4 v = *reinterpret_cast<const float4*>(tr + row * 68 + (lane & 15) * 4);
      long gr = batch0 + mt * 16 + row;
      *reinterpret_cast<float4*>(out + gr * 64 + (lane & 15) * 4) = v;
    }
    __asm__ volatile("s_waitcnt lgkmcnt(0)" ::: "memory");
  }
}

// ---------------------------------------------------------------------------
extern "C" void kernel_launch(void* const* d_in, const int* in_sizes, int n_in,
                              void* d_out, int out_size, void* d_ws, size_t ws_size,
                              hipStream_t stream) {
  const float* x        = (const float*)d_in[0];
  const float* w_start  = (const float*)d_in[1];
  const float* b_start  = (const float*)d_in[2];
  const float* masked_w = (const float*)d_in[3];
  const float* layer_b  = (const float*)d_in[4];
  const float* w_out    = (const float*)d_in[5];
  const float* b_out    = (const float*)d_in[6];
  uint16_t* wfrag = (uint16_t*)d_ws;   // 67 chunks x 16640 B = 1,114,880 B

  prep_frags<<<273, 256, 0, stream>>>(w_start, b_start, masked_w, layer_b,
                                      w_out, b_out, wfrag);
  wann_main<<<512, 512, 49920, stream>>>(x, wfrag, (float*)d_out);
}

// Round 5
// 290.770 us; speedup vs baseline: 1.2245x; 1.2245x over previous
//
#include <hip/hip_runtime.h>
#include <hip/hip_bf16.h>
#include <stdint.h>

// ---------------------------------------------------------------------------
// wannModel: x0 = x@Ws^T + bs;  h_{l+1} = relu(h_l@W_l^T + b_l) + x0 (32x);
//            out = softmax(h@Wo^T + bo)  over 64 classes.
//
// Transposed-orientation MFMA chain (out^T = W * h^T). k-index mismatch
// absorbed by pre-permuting weights' k axis (pi) in a prep kernel. h stays
// in registers across all 32 layers (mt=2: 32 rows/wave, 12 waves/CU).
//
// R10 post-mortem: launch_bounds(512,4) joint budget 128 < ~168 demand ->
// spill storm (FETCH 111MB, WRITE 99MB). Tail died (Occ 41%) but spills ate
// it. PROVEN: mt=2 demand caps occupancy at 3 waves/SIMD; the 4096-tile /
// 3072-slot ratio makes a residency tail structural.
// R11: delete the cooperative structure. Weights (1.1MB) are L2-resident in
// every XCD (and L1-hot: 12 waves/CU stream the same 32KB sequence).
// Read fragments DIRECTLY from L2 -> no LDS staging, no barriers, no
// lockstep; every wave free-runs, the 256-block tail streams at full
// per-CU L2 BW (~10us, was 87us). Floor: 4.2GB weight traffic / 34.5TB/s
// ~= 122us, overlapped with 70us MFMA. LDS = softmax scratch only.
// ---------------------------------------------------------------------------

typedef short bs8 __attribute__((ext_vector_type(8)));   // 8 x bf16 bits
typedef float f32x4 __attribute__((ext_vector_type(4)));

union Frag { bs8 v; uint32_t u[4]; };
union F4   { float4 f; f32x4 v; };

__device__ __forceinline__ uint32_t cvtpk(float lo, float hi) {
#if __has_builtin(__builtin_amdgcn_cvt_pk_bf16_f32)
  auto r = __builtin_amdgcn_cvt_pk_bf16_f32(lo, hi);   // dst.lo=cvt(lo)
  uint32_t u; __builtin_memcpy(&u, &r, 4);
  return u;
#else
  union { float f; uint32_t u; } a, b; a.f = lo; b.f = hi;
  uint32_t ra = a.u + 0x7fffu + ((a.u >> 16) & 1u);    // RNE, no NaN check
  uint32_t rb = b.u + 0x7fffu + ((b.u >> 16) & 1u);
  return (ra >> 16) | (rb & 0xffff0000u);
#endif
}

// ---------------------------------------------------------------------------
// Preprocess. Chunk layout in d_ws (uint16 units, 8320 elems = 16640 B each):
//   chunk c base = c*8320.  [0,8192) = weight frags (4 ntloc x 4 kt),
//   [8192,8320) = 256 B bias (64 floats for this half-layer).
// Chunks: 0,1 = W_start halves (NATURAL k) + b_start halves;
//         2+2l+h = layer l half h (PI-permuted k) + layer_b[l] half h;
//         66 = W_out (4 nt, PI-permuted) + b_out (64 floats).
// Weight element in chunk: ((ntloc*4+kt)*64 + lane)*8 + j.
// ---------------------------------------------------------------------------
__global__ void prep_frags(const float* __restrict__ w_start,
                           const float* __restrict__ b_start,
                           const float* __restrict__ masked_w,
                           const float* __restrict__ layer_b,
                           const float* __restrict__ w_out,
                           const float* __restrict__ b_out,
                           uint16_t* __restrict__ dst) {
  int t = blockIdx.x * 256 + threadIdx.x;
  if (t >= 69680) return;
  if (t >= 68608) {                            // bias floats, 4 per thread
    int f = (t - 68608) * 4;
    int c, off; const float* src;
    if (f < 128)       { c = f >> 6;               off = f & 63; src = b_start + f; }
    else if (f < 4224) { int g = f - 128;  c = 2 + (g >> 6); off = g & 63; src = layer_b + g; }
    else               { int g = f - 4224; c = 66;           off = g;      src = b_out + g; }
    float4 v = *reinterpret_cast<const float4*>(src);
    *reinterpret_cast<float4*>(
        reinterpret_cast<float*>(dst + (size_t)c * 8320 + 8192) + off) = v;
    return;
  }
  int lane = t & 63, kt = (t >> 6) & 3, q = lane >> 4, m15 = lane & 15;
  float f[8];
  int c, ntloc;
  if (t < 2048) {                              // W_start (natural k)
    int nt = (t >> 8) & 7;
    c = nt >> 2; ntloc = nt & 3;
    const float* s = w_start + (nt * 16 + m15) * 128 + q * 8 + kt * 32;
    #pragma unroll
    for (int j = 0; j < 8; ++j) f[j] = s[j];
  } else if (t < 67584) {                      // chain (pi-permuted k)
    int t2 = t - 2048, l = t2 >> 11, nt = (t2 >> 8) & 7;
    c = 2 + 2 * l + (nt >> 2); ntloc = nt & 3;
    const float* s = masked_w + ((l * 128) + nt * 16 + m15) * 128 + q * 4 + kt * 32;
    #pragma unroll
    for (int j = 0; j < 8; ++j) f[j] = s[(j & 3) + 16 * (j >> 2)];
  } else {                                     // W_out (pi-permuted k)
    int t3 = t - 67584, nt = (t3 >> 8) & 3;
    c = 66; ntloc = nt;
    const float* s = w_out + (nt * 16 + m15) * 128 + q * 4 + kt * 32;
    #pragma unroll
    for (int j = 0; j < 8; ++j) f[j] = s[(j & 3) + 16 * (j >> 2)];
  }
  uint4 o;
  o.x = cvtpk(f[0], f[1]); o.y = cvtpk(f[2], f[3]);
  o.z = cvtpk(f[4], f[5]); o.w = cvtpk(f[6], f[7]);
  *reinterpret_cast<uint4*>(dst + (size_t)c * 8320 +
                            ((ntloc * 4 + kt) * 64 + lane) * 8) = o;
}

// ---------------------------------------------------------------------------
// Main kernel: 1024 blocks x 256 threads (4 waves; wave owns 32 batch cols
// = 2 m-tiles of 16). NO LDS staging, NO barriers: weight fragments are
// read per-wave straight from L2/L1 (1.1MB working set, L2-resident).
// LDS = 17408 B softmax transpose scratch only (per-wave private).
// 12 waves/CU resident (reg-limited); all waves free-run.
// ---------------------------------------------------------------------------
extern __shared__ uint16_t lds[];

__global__ void __launch_bounds__(256, 3)
wann_main(const float* __restrict__ x,
          const uint16_t* __restrict__ wfrag,
          float* __restrict__ out) {
  const int tid  = threadIdx.x;
  const int lane = tid & 63;
  const int wave = tid >> 6;
  const int q    = lane >> 4;
  const int mc   = lane & 15;
  const long batch0 = (long)blockIdx.x * 128 + wave * 32;
  const f32x4 zero4 = {0.f, 0.f, 0.f, 0.f};

  // per-lane base into a chunk's weight region (uint16 units)
  const int lane8 = lane * 8;

  // ---- load x fragments (natural k: B[k=8q+j+32kt][batch=mc]) ----
  Frag xf[2][4];
  #pragma unroll
  for (int mt = 0; mt < 2; ++mt) {
    const float* xrow = x + (batch0 + mt * 16 + mc) * 128 + q * 8;
    #pragma unroll
    for (int kt = 0; kt < 4; ++kt) {
      float4 a = *reinterpret_cast<const float4*>(xrow + kt * 32);
      float4 b = *reinterpret_cast<const float4*>(xrow + kt * 32 + 4);
      xf[mt][kt].u[0] = cvtpk(a.x, a.y);
      xf[mt][kt].u[1] = cvtpk(a.z, a.w);
      xf[mt][kt].u[2] = cvtpk(b.x, b.y);
      xf[mt][kt].u[3] = cvtpk(b.z, b.w);
    }
  }

  Frag x0f[2][4], hA[2][4], hB[2][4];

  // ---- start layer: chunks 0,1 (natural k), input xf, out x0f ----
  #pragma unroll
  for (int nt = 0; nt < 8; ++nt) {
    const uint16_t* cb = wfrag + (size_t)(nt >> 2) * 8320;   // chunk base
    const int ntloc = nt & 3;
    const uint16_t* wb = cb + ntloc * 2048 + lane8;
    F4 bb;
    bb.f = *reinterpret_cast<const float4*>(
        reinterpret_cast<const float*>(cb + 8192) + ntloc * 16 + q * 4);
    Frag wf0, wf1, wf2, wf3;
    wf0.v = *reinterpret_cast<const bs8*>(wb);
    wf1.v = *reinterpret_cast<const bs8*>(wb + 512);
    wf2.v = *reinterpret_cast<const bs8*>(wb + 1024);
    wf3.v = *reinterpret_cast<const bs8*>(wb + 1536);
    f32x4 acc[2];
    __builtin_amdgcn_s_setprio(1);
    #pragma unroll
    for (int mt = 0; mt < 2; ++mt)
      acc[mt] = __builtin_amdgcn_mfma_f32_16x16x32_bf16(wf0.v, xf[mt][0].v, bb.v, 0, 0, 0);
    #pragma unroll
    for (int mt = 0; mt < 2; ++mt)
      acc[mt] = __builtin_amdgcn_mfma_f32_16x16x32_bf16(wf1.v, xf[mt][1].v, acc[mt], 0, 0, 0);
    #pragma unroll
    for (int mt = 0; mt < 2; ++mt)
      acc[mt] = __builtin_amdgcn_mfma_f32_16x16x32_bf16(wf2.v, xf[mt][2].v, acc[mt], 0, 0, 0);
    #pragma unroll
    for (int mt = 0; mt < 2; ++mt)
      acc[mt] = __builtin_amdgcn_mfma_f32_16x16x32_bf16(wf3.v, xf[mt][3].v, acc[mt], 0, 0, 0);
    __builtin_amdgcn_s_setprio(0);
    #pragma unroll
    for (int mt = 0; mt < 2; ++mt) {
      x0f[mt][nt >> 1].u[2 * (nt & 1) + 0] = cvtpk(acc[mt][0], acc[mt][1]);
      x0f[mt][nt >> 1].u[2 * (nt & 1) + 1] = cvtpk(acc[mt][2], acc[mt][3]);
    }
  }
  #pragma unroll
  for (int mt = 0; mt < 2; ++mt)
    #pragma unroll
    for (int kt = 0; kt < 4; ++kt)
      hA[mt][kt].v = x0f[mt][kt].v;          // h = x0

  // ---- chain layer body (weights straight from L2) ----
  auto chain_layer = [&](uint32_t l, Frag (&hin)[2][4], Frag (&hout)[2][4]) {
    const uint16_t* lb = wfrag + (size_t)(2 + 2 * l) * 8320;
    #pragma unroll
    for (int nt = 0; nt < 8; ++nt) {
      const uint16_t* cb = lb + (size_t)(nt >> 2) * 8320;
      const int ntloc = nt & 3;
      const uint16_t* wb = cb + ntloc * 2048 + lane8;
      F4 bb;
      bb.f = *reinterpret_cast<const float4*>(
          reinterpret_cast<const float*>(cb + 8192) + ntloc * 16 + q * 4);
      Frag wf0, wf1, wf2, wf3;
      wf0.v = *reinterpret_cast<const bs8*>(wb);
      wf1.v = *reinterpret_cast<const bs8*>(wb + 512);
      wf2.v = *reinterpret_cast<const bs8*>(wb + 1024);
      wf3.v = *reinterpret_cast<const bs8*>(wb + 1536);
      f32x4 acc[2];
      __builtin_amdgcn_s_setprio(1);
      #pragma unroll
      for (int mt = 0; mt < 2; ++mt)
        acc[mt] = __builtin_amdgcn_mfma_f32_16x16x32_bf16(wf0.v, hin[mt][0].v, bb.v, 0, 0, 0);
      #pragma unroll
      for (int mt = 0; mt < 2; ++mt)
        acc[mt] = __builtin_amdgcn_mfma_f32_16x16x32_bf16(wf1.v, hin[mt][1].v, acc[mt], 0, 0, 0);
      #pragma unroll
      for (int mt = 0; mt < 2; ++mt)
        acc[mt] = __builtin_amdgcn_mfma_f32_16x16x32_bf16(wf2.v, hin[mt][2].v, acc[mt], 0, 0, 0);
      #pragma unroll
      for (int mt = 0; mt < 2; ++mt)
        acc[mt] = __builtin_amdgcn_mfma_f32_16x16x32_bf16(wf3.v, hin[mt][3].v, acc[mt], 0, 0, 0);
      __builtin_amdgcn_s_setprio(0);
      #pragma unroll
      for (int mt = 0; mt < 2; ++mt) {
        f32x4 r = __builtin_elementwise_max(acc[mt], zero4);
        uint32_t xw0 = x0f[mt][nt >> 1].u[2 * (nt & 1) + 0];
        uint32_t xw1 = x0f[mt][nt >> 1].u[2 * (nt & 1) + 1];
        f32x4 xv;
        xv[0] = __uint_as_float(xw0 << 16);
        xv[1] = __uint_as_float(xw0 & 0xffff0000u);
        xv[2] = __uint_as_float(xw1 << 16);
        xv[3] = __uint_as_float(xw1 & 0xffff0000u);
        r = r + xv;
        hout[mt][nt >> 1].u[2 * (nt & 1) + 0] = cvtpk(r[0], r[1]);
        hout[mt][nt >> 1].u[2 * (nt & 1) + 1] = cvtpk(r[2], r[3]);
      }
    }
  };

  // ---- 32 layers; h ping-pong via 2x unroll ----
  #pragma unroll 1
  for (uint32_t l = 0; l < 32; l += 2) {
    chain_layer(l, hA, hB);
    chain_layer(l + 1, hB, hA);
  }

  // ---- output layer: chunk 66 (W_out + b_out) from L2 ----
  const uint16_t* wo = wfrag + (size_t)66 * 8320;
  const float* bob = reinterpret_cast<const float*>(wo + 8192);
  f32x4 ao[4][2];  // [nt][mt]
  #pragma unroll
  for (int nt = 0; nt < 4; ++nt) {
    const uint16_t* wb = wo + nt * 2048 + lane8;
    F4 bo;
    bo.f = *reinterpret_cast<const float4*>(bob + nt * 16 + q * 4);
    Frag wf0, wf1, wf2, wf3;
    wf0.v = *reinterpret_cast<const bs8*>(wb);
    wf1.v = *reinterpret_cast<const bs8*>(wb + 512);
    wf2.v = *reinterpret_cast<const bs8*>(wb + 1024);
    wf3.v = *reinterpret_cast<const bs8*>(wb + 1536);
    __builtin_amdgcn_s_setprio(1);
    #pragma unroll
    for (int mt = 0; mt < 2; ++mt)
      ao[nt][mt] = __builtin_amdgcn_mfma_f32_16x16x32_bf16(wf0.v, hA[mt][0].v, bo.v, 0, 0, 0);
    #pragma unroll
    for (int mt = 0; mt < 2; ++mt)
      ao[nt][mt] = __builtin_amdgcn_mfma_f32_16x16x32_bf16(wf1.v, hA[mt][1].v, ao[nt][mt], 0, 0, 0);
    #pragma unroll
    for (int mt = 0; mt < 2; ++mt)
      ao[nt][mt] = __builtin_amdgcn_mfma_f32_16x16x32_bf16(wf2.v, hA[mt][2].v, ao[nt][mt], 0, 0, 0);
    #pragma unroll
    for (int mt = 0; mt < 2; ++mt)
      ao[nt][mt] = __builtin_amdgcn_mfma_f32_16x16x32_bf16(wf3.v, hA[mt][3].v, ao[nt][mt], 0, 0, 0);
    __builtin_amdgcn_s_setprio(0);
  }

  // ---- softmax over 64 classes + transposed store via LDS scratch ----
  // LDS is per-wave private scratch (no cross-wave sharing -> no barrier).
  float* tr = reinterpret_cast<float*>(lds) + wave * 1088;   // 16x68 floats
  #pragma unroll
  for (int mt = 0; mt < 2; ++mt) {
    float e[16];
    float M = -3.0e38f;
    #pragma unroll
    for (int nt = 0; nt < 4; ++nt)
      #pragma unroll
      for (int r = 0; r < 4; ++r)
        M = fmaxf(M, ao[nt][mt][r]);
    M = fmaxf(M, __shfl_xor(M, 16, 64));
    M = fmaxf(M, __shfl_xor(M, 32, 64));
    float S = 0.0f;
    #pragma unroll
    for (int nt = 0; nt < 4; ++nt)
      #pragma unroll
      for (int r = 0; r < 4; ++r) {
        float t = exp2f((ao[nt][mt][r] - M) * 1.4426950408889634f);
        e[nt * 4 + r] = t;
        S += t;
      }
    S += __shfl_xor(S, 16, 64);
    S += __shfl_xor(S, 32, 64);
    const float inv = 1.0f / S;
    #pragma unroll
    for (int nt = 0; nt < 4; ++nt) {
      float4 pv;
      pv.x = e[nt * 4 + 0] * inv;
      pv.y = e[nt * 4 + 1] * inv;
      pv.z = e[nt * 4 + 2] * inv;
      pv.w = e[nt * 4 + 3] * inv;
      *reinterpret_cast<float4*>(tr + mc * 68 + nt * 16 + q * 4) = pv;
    }
    __asm__ volatile("s_waitcnt lgkmcnt(0)" ::: "memory");
    #pragma unroll
    for (int it = 0; it < 4; ++it) {
      int row = it * 4 + (lane >> 4);
      float4 v = *reinterpret_cast<const float4*>(tr + row * 68 + (lane & 15) * 4);
      long gr = batch0 + mt * 16 + row;
      *reinterpret_cast<float4*>(out + gr * 64 + (lane & 15) * 4) = v;
    }
    __asm__ volatile("s_waitcnt lgkmcnt(0)" ::: "memory");
  }
}

// ---------------------------------------------------------------------------
extern "C" void kernel_launch(void* const* d_in, const int* in_sizes, int n_in,
                              void* d_out, int out_size, void* d_ws, size_t ws_size,
                              hipStream_t stream) {
  const float* x        = (const float*)d_in[0];
  const float* w_start  = (const float*)d_in[1];
  const float* b_start  = (const float*)d_in[2];
  const float* masked_w = (const float*)d_in[3];
  const float* layer_b  = (const float*)d_in[4];
  const float* w_out    = (const float*)d_in[5];
  const float* b_out    = (const float*)d_in[6];
  uint16_t* wfrag = (uint16_t*)d_ws;   // 67 chunks x 16640 B = 1,114,880 B

  prep_frags<<<273, 256, 0, stream>>>(w_start, b_start, masked_w, layer_b,
                                      w_out, b_out, wfrag);
  wann_main<<<1024, 256, 17408, stream>>>(x, wfrag, (float*)d_out);
}

// Round 6
// 276.763 us; speedup vs baseline: 1.2865x; 1.0506x over previous
//
#include <hip/hip_runtime.h>
#include <hip/hip_bf16.h>
#include <stdint.h>

// ---------------------------------------------------------------------------
// wannModel: x0 = x@Ws^T + bs;  h_{l+1} = relu(h_l@W_l^T + b_l) + x0 (32x);
//            out = softmax(h@Wo^T + bo)  over 64 classes.
//
// Transposed-orientation MFMA chain (out^T = W * h^T). k-index mismatch
// absorbed by pre-permuting weights' k axis (pi) in a prep kernel.
//
// R11 post-mortem: L2-direct at mt=2 kept the 1.33-round tail (Occ 26%) and
// has a 125us L2 floor (4.3GB weight traffic). Ledger: tail is structural
// at mt=2 (4096 waves / 3072 reg-limited slots); register fixes fail on
// mt=2's 96-reg h/x0 state.
// R12: mt=4 (64 rows/wave) + x0 moved to per-wave-private LDS:
//   - waves 4096->2048 = 512 blocks = EXACTLY 2 blocks/CU, zero tail;
//   - L2 weight traffic halves: 2048x33x32KB = 2.2GB ~= 60us floor;
//   - reg state: hA 64 + hB 64 + acc 16 + wf 16 + misc ~= 184 <= 256
//     budget at launch_bounds(256,2)  (R8 spilled because x0f's 64 regs
//     pushed it to ~250; x0-in-LDS is the difference);
//   - x0 LDS: 16KB/wave, layout [pair][lane][2] -> conflict-free
//     ds_read_b64, one per mt per pass; NO barriers anywhere (LDS is
//     per-wave private; softmax scratch reuses the region after layer 31).
// Floors: MFMA 68us, L2 60us, VALU ~45us, LDS 14us -> overlapped target
// ~120-160us.
// ---------------------------------------------------------------------------

typedef short bs8 __attribute__((ext_vector_type(8)));   // 8 x bf16 bits
typedef float f32x4 __attribute__((ext_vector_type(4)));

union Frag { bs8 v; uint32_t u[4]; };
union F4   { float4 f; f32x4 v; };

__device__ __forceinline__ uint32_t cvtpk(float lo, float hi) {
#if __has_builtin(__builtin_amdgcn_cvt_pk_bf16_f32)
  auto r = __builtin_amdgcn_cvt_pk_bf16_f32(lo, hi);   // dst.lo=cvt(lo)
  uint32_t u; __builtin_memcpy(&u, &r, 4);
  return u;
#else
  union { float f; uint32_t u; } a, b; a.f = lo; b.f = hi;
  uint32_t ra = a.u + 0x7fffu + ((a.u >> 16) & 1u);    // RNE, no NaN check
  uint32_t rb = b.u + 0x7fffu + ((b.u >> 16) & 1u);
  return (ra >> 16) | (rb & 0xffff0000u);
#endif
}

// ---------------------------------------------------------------------------
// Preprocess. Chunk layout in d_ws (uint16 units, 8320 elems = 16640 B each):
//   chunk c base = c*8320.  [0,8192) = weight frags (4 ntloc x 4 kt),
//   [8192,8320) = 256 B bias (64 floats for this half-layer).
// Chunks: 0,1 = W_start halves (NATURAL k) + b_start halves;
//         2+2l+h = layer l half h (PI-permuted k) + layer_b[l] half h;
//         66 = W_out (4 nt, PI-permuted) + b_out (64 floats).
// Weight element in chunk: ((ntloc*4+kt)*64 + lane)*8 + j.
// ---------------------------------------------------------------------------
__global__ void prep_frags(const float* __restrict__ w_start,
                           const float* __restrict__ b_start,
                           const float* __restrict__ masked_w,
                           const float* __restrict__ layer_b,
                           const float* __restrict__ w_out,
                           const float* __restrict__ b_out,
                           uint16_t* __restrict__ dst) {
  int t = blockIdx.x * 256 + threadIdx.x;
  if (t >= 69680) return;
  if (t >= 68608) {                            // bias floats, 4 per thread
    int f = (t - 68608) * 4;
    int c, off; const float* src;
    if (f < 128)       { c = f >> 6;               off = f & 63; src = b_start + f; }
    else if (f < 4224) { int g = f - 128;  c = 2 + (g >> 6); off = g & 63; src = layer_b + g; }
    else               { int g = f - 4224; c = 66;           off = g;      src = b_out + g; }
    float4 v = *reinterpret_cast<const float4*>(src);
    *reinterpret_cast<float4*>(
        reinterpret_cast<float*>(dst + (size_t)c * 8320 + 8192) + off) = v;
    return;
  }
  int lane = t & 63, kt = (t >> 6) & 3, q = lane >> 4, m15 = lane & 15;
  float f[8];
  int c, ntloc;
  if (t < 2048) {                              // W_start (natural k)
    int nt = (t >> 8) & 7;
    c = nt >> 2; ntloc = nt & 3;
    const float* s = w_start + (nt * 16 + m15) * 128 + q * 8 + kt * 32;
    #pragma unroll
    for (int j = 0; j < 8; ++j) f[j] = s[j];
  } else if (t < 67584) {                      // chain (pi-permuted k)
    int t2 = t - 2048, l = t2 >> 11, nt = (t2 >> 8) & 7;
    c = 2 + 2 * l + (nt >> 2); ntloc = nt & 3;
    const float* s = masked_w + ((l * 128) + nt * 16 + m15) * 128 + q * 4 + kt * 32;
    #pragma unroll
    for (int j = 0; j < 8; ++j) f[j] = s[(j & 3) + 16 * (j >> 2)];
  } else {                                     // W_out (pi-permuted k)
    int t3 = t - 67584, nt = (t3 >> 8) & 3;
    c = 66; ntloc = nt;
    const float* s = w_out + (nt * 16 + m15) * 128 + q * 4 + kt * 32;
    #pragma unroll
    for (int j = 0; j < 8; ++j) f[j] = s[(j & 3) + 16 * (j >> 2)];
  }
  uint4 o;
  o.x = cvtpk(f[0], f[1]); o.y = cvtpk(f[2], f[3]);
  o.z = cvtpk(f[4], f[5]); o.w = cvtpk(f[6], f[7]);
  *reinterpret_cast<uint4*>(dst + (size_t)c * 8320 +
                            ((ntloc * 4 + kt) * 64 + lane) * 8) = o;
}

// ---------------------------------------------------------------------------
// Main kernel: 512 blocks x 256 threads (4 waves; wave owns 64 batch cols
// = 4 m-tiles of 16). NO barriers, NO weight staging: weights straight from
// L2 (1.1MB resident). LDS 64KB = 4 waves x 16KB private x0 store
// ([pair][lane][2 u32] layout, pair = (mt*4+p)*2+h), reused as softmax
// transpose scratch after the chain. Exactly 2 blocks/CU, one dispatch
// round, zero tail; all waves free-run.
// ---------------------------------------------------------------------------
extern __shared__ uint16_t lds[];

__global__ void __launch_bounds__(256, 2)
wann_main(const float* __restrict__ x,
          const uint16_t* __restrict__ wfrag,
          float* __restrict__ out) {
  const int tid  = threadIdx.x;
  const int lane = tid & 63;
  const int wave = tid >> 6;
  const int q    = lane >> 4;
  const int mc   = lane & 15;
  const long batch0 = (long)blockIdx.x * 256 + wave * 64;
  const f32x4 zero4 = {0.f, 0.f, 0.f, 0.f};

  const int lane8 = lane * 8;

  // per-wave private x0 store: 4096 u32 (16KB). pair (mt,p,h) at
  // u32 offset pair*128 + lane*2, 2 consecutive u32 -> ds_read/write_b64.
  uint32_t* x0l = reinterpret_cast<uint32_t*>(lds) + wave * 4096;

  // ---- load x fragments (natural k: B[k=8q+j+32kt][batch=mc]) ----
  Frag xf[4][4];
  #pragma unroll
  for (int mt = 0; mt < 4; ++mt) {
    const float* xrow = x + (batch0 + mt * 16 + mc) * 128 + q * 8;
    #pragma unroll
    for (int kt = 0; kt < 4; ++kt) {
      float4 a = *reinterpret_cast<const float4*>(xrow + kt * 32);
      float4 b = *reinterpret_cast<const float4*>(xrow + kt * 32 + 4);
      xf[mt][kt].u[0] = cvtpk(a.x, a.y);
      xf[mt][kt].u[1] = cvtpk(a.z, a.w);
      xf[mt][kt].u[2] = cvtpk(b.x, b.y);
      xf[mt][kt].u[3] = cvtpk(b.z, b.w);
    }
  }

  Frag hA[4][4], hB[4][4];

  // ---- start layer: chunks 0,1 (natural k); x0 -> LDS and hA ----
  #pragma unroll
  for (int nt = 0; nt < 8; ++nt) {
    const uint16_t* cb = wfrag + (size_t)(nt >> 2) * 8320;   // chunk base
    const int ntloc = nt & 3;
    const uint16_t* wb = cb + ntloc * 2048 + lane8;
    F4 bb;
    bb.f = *reinterpret_cast<const float4*>(
        reinterpret_cast<const float*>(cb + 8192) + ntloc * 16 + q * 4);
    Frag wf0, wf1, wf2, wf3;
    wf0.v = *reinterpret_cast<const bs8*>(wb);
    wf1.v = *reinterpret_cast<const bs8*>(wb + 512);
    wf2.v = *reinterpret_cast<const bs8*>(wb + 1024);
    wf3.v = *reinterpret_cast<const bs8*>(wb + 1536);
    f32x4 acc[4];
    __builtin_amdgcn_s_setprio(1);
    #pragma unroll
    for (int mt = 0; mt < 4; ++mt)
      acc[mt] = __builtin_amdgcn_mfma_f32_16x16x32_bf16(wf0.v, xf[mt][0].v, bb.v, 0, 0, 0);
    #pragma unroll
    for (int mt = 0; mt < 4; ++mt)
      acc[mt] = __builtin_amdgcn_mfma_f32_16x16x32_bf16(wf1.v, xf[mt][1].v, acc[mt], 0, 0, 0);
    #pragma unroll
    for (int mt = 0; mt < 4; ++mt)
      acc[mt] = __builtin_amdgcn_mfma_f32_16x16x32_bf16(wf2.v, xf[mt][2].v, acc[mt], 0, 0, 0);
    #pragma unroll
    for (int mt = 0; mt < 4; ++mt)
      acc[mt] = __builtin_amdgcn_mfma_f32_16x16x32_bf16(wf3.v, xf[mt][3].v, acc[mt], 0, 0, 0);
    __builtin_amdgcn_s_setprio(0);
    const int p = nt >> 1, h = nt & 1;
    #pragma unroll
    for (int mt = 0; mt < 4; ++mt) {
      uint32_t w0 = cvtpk(acc[mt][0], acc[mt][1]);
      uint32_t w1 = cvtpk(acc[mt][2], acc[mt][3]);
      hA[mt][p].u[2 * h + 0] = w0;
      hA[mt][p].u[2 * h + 1] = w1;
      uint32_t* xp = x0l + ((mt * 4 + p) * 2 + h) * 128 + lane * 2;
      xp[0] = w0; xp[1] = w1;
    }
  }

  // ---- chain layer body (weights from L2, x0 from private LDS) ----
  auto chain_layer = [&](uint32_t l, Frag (&hin)[4][4], Frag (&hout)[4][4]) {
    const uint16_t* lb = wfrag + (size_t)(2 + 2 * l) * 8320;
    #pragma unroll
    for (int nt = 0; nt < 8; ++nt) {
      const uint16_t* cb = lb + (size_t)(nt >> 2) * 8320;
      const int ntloc = nt & 3;
      const uint16_t* wb = cb + ntloc * 2048 + lane8;
      F4 bb;
      bb.f = *reinterpret_cast<const float4*>(
          reinterpret_cast<const float*>(cb + 8192) + ntloc * 16 + q * 4);
      Frag wf0, wf1, wf2, wf3;
      wf0.v = *reinterpret_cast<const bs8*>(wb);
      wf1.v = *reinterpret_cast<const bs8*>(wb + 512);
      wf2.v = *reinterpret_cast<const bs8*>(wb + 1024);
      wf3.v = *reinterpret_cast<const bs8*>(wb + 1536);
      f32x4 acc[4];
      __builtin_amdgcn_s_setprio(1);
      #pragma unroll
      for (int mt = 0; mt < 4; ++mt)
        acc[mt] = __builtin_amdgcn_mfma_f32_16x16x32_bf16(wf0.v, hin[mt][0].v, bb.v, 0, 0, 0);
      #pragma unroll
      for (int mt = 0; mt < 4; ++mt)
        acc[mt] = __builtin_amdgcn_mfma_f32_16x16x32_bf16(wf1.v, hin[mt][1].v, acc[mt], 0, 0, 0);
      #pragma unroll
      for (int mt = 0; mt < 4; ++mt)
        acc[mt] = __builtin_amdgcn_mfma_f32_16x16x32_bf16(wf2.v, hin[mt][2].v, acc[mt], 0, 0, 0);
      #pragma unroll
      for (int mt = 0; mt < 4; ++mt)
        acc[mt] = __builtin_amdgcn_mfma_f32_16x16x32_bf16(wf3.v, hin[mt][3].v, acc[mt], 0, 0, 0);
      __builtin_amdgcn_s_setprio(0);
      const int p = nt >> 1, h = nt & 1;
      #pragma unroll
      for (int mt = 0; mt < 4; ++mt) {
        const uint32_t* xp = x0l + ((mt * 4 + p) * 2 + h) * 128 + lane * 2;
        uint32_t xw0 = xp[0];
        uint32_t xw1 = xp[1];
        f32x4 r = __builtin_elementwise_max(acc[mt], zero4);
        f32x4 xv;
        xv[0] = __uint_as_float(xw0 << 16);
        xv[1] = __uint_as_float(xw0 & 0xffff0000u);
        xv[2] = __uint_as_float(xw1 << 16);
        xv[3] = __uint_as_float(xw1 & 0xffff0000u);
        r = r + xv;
        hout[mt][p].u[2 * h + 0] = cvtpk(r[0], r[1]);
        hout[mt][p].u[2 * h + 1] = cvtpk(r[2], r[3]);
      }
    }
  };

  // ---- 32 layers; h ping-pong via 2x unroll ----
  #pragma unroll 1
  for (uint32_t l = 0; l < 32; l += 2) {
    chain_layer(l, hA, hB);
    chain_layer(l + 1, hB, hA);
  }

  // ---- output layer: chunk 66 (W_out + b_out) from L2 ----
  const uint16_t* wo = wfrag + (size_t)66 * 8320;
  const float* bob = reinterpret_cast<const float*>(wo + 8192);
  f32x4 ao[4][4];  // [nt][mt]
  #pragma unroll
  for (int nt = 0; nt < 4; ++nt) {
    const uint16_t* wb = wo + nt * 2048 + lane8;
    F4 bo;
    bo.f = *reinterpret_cast<const float4*>(bob + nt * 16 + q * 4);
    Frag wf0, wf1, wf2, wf3;
    wf0.v = *reinterpret_cast<const bs8*>(wb);
    wf1.v = *reinterpret_cast<const bs8*>(wb + 512);
    wf2.v = *reinterpret_cast<const bs8*>(wb + 1024);
    wf3.v = *reinterpret_cast<const bs8*>(wb + 1536);
    __builtin_amdgcn_s_setprio(1);
    #pragma unroll
    for (int mt = 0; mt < 4; ++mt)
      ao[nt][mt] = __builtin_amdgcn_mfma_f32_16x16x32_bf16(wf0.v, hA[mt][0].v, bo.v, 0, 0, 0);
    #pragma unroll
    for (int mt = 0; mt < 4; ++mt)
      ao[nt][mt] = __builtin_amdgcn_mfma_f32_16x16x32_bf16(wf1.v, hA[mt][1].v, ao[nt][mt], 0, 0, 0);
    #pragma unroll
    for (int mt = 0; mt < 4; ++mt)
      ao[nt][mt] = __builtin_amdgcn_mfma_f32_16x16x32_bf16(wf2.v, hA[mt][2].v, ao[nt][mt], 0, 0, 0);
    #pragma unroll
    for (int mt = 0; mt < 4; ++mt)
      ao[nt][mt] = __builtin_amdgcn_mfma_f32_16x16x32_bf16(wf3.v, hA[mt][3].v, ao[nt][mt], 0, 0, 0);
    __builtin_amdgcn_s_setprio(0);
  }

  // ---- softmax over 64 classes + transposed store via LDS scratch ----
  // x0 region is dead now; reuse the wave's private 16KB as scratch.
  float* tr = reinterpret_cast<float*>(x0l);   // 16x68 floats per mt pass
  #pragma unroll
  for (int mt = 0; mt < 4; ++mt) {
    float e[16];
    float M = -3.0e38f;
    #pragma unroll
    for (int nt = 0; nt < 4; ++nt)
      #pragma unroll
      for (int r = 0; r < 4; ++r)
        M = fmaxf(M, ao[nt][mt][r]);
    M = fmaxf(M, __shfl_xor(M, 16, 64));
    M = fmaxf(M, __shfl_xor(M, 32, 64));
    float S = 0.0f;
    #pragma unroll
    for (int nt = 0; nt < 4; ++nt)
      #pragma unroll
      for (int r = 0; r < 4; ++r) {
        float t = exp2f((ao[nt][mt][r] - M) * 1.4426950408889634f);
        e[nt * 4 + r] = t;
        S += t;
      }
    S += __shfl_xor(S, 16, 64);
    S += __shfl_xor(S, 32, 64);
    const float inv = 1.0f / S;
    #pragma unroll
    for (int nt = 0; nt < 4; ++nt) {
      float4 pv;
      pv.x = e[nt * 4 + 0] * inv;
      pv.y = e[nt * 4 + 1] * inv;
      pv.z = e[nt * 4 + 2] * inv;
      pv.w = e[nt * 4 + 3] * inv;
      *reinterpret_cast<float4*>(tr + mc * 68 + nt * 16 + q * 4) = pv;
    }
    __asm__ volatile("s_waitcnt lgkmcnt(0)" ::: "memory");
    #pragma unroll
    for (int it = 0; it < 4; ++it) {
      int row = it * 4 + (lane >> 4);
      float4 v = *reinterpret_cast<const float4*>(tr + row * 68 + (lane & 15) * 4);
      long gr = batch0 + mt * 16 + row;
      *reinterpret_cast<float4*>(out + gr * 64 + (lane & 15) * 4) = v;
    }
    __asm__ volatile("s_waitcnt lgkmcnt(0)" ::: "memory");
  }
}

// ---------------------------------------------------------------------------
extern "C" void kernel_launch(void* const* d_in, const int* in_sizes, int n_in,
                              void* d_out, int out_size, void* d_ws, size_t ws_size,
                              hipStream_t stream) {
  const float* x        = (const float*)d_in[0];
  const float* w_start  = (const float*)d_in[1];
  const float* b_start  = (const float*)d_in[2];
  const float* masked_w = (const float*)d_in[3];
  const float* layer_b  = (const float*)d_in[4];
  const float* w_out    = (const float*)d_in[5];
  const float* b_out    = (const float*)d_in[6];
  uint16_t* wfrag = (uint16_t*)d_ws;   // 67 chunks x 16640 B = 1,114,880 B

  prep_frags<<<273, 256, 0, stream>>>(w_start, b_start, masked_w, layer_b,
                                      w_out, b_out, wfrag);
  wann_main<<<512, 256, 65536, stream>>>(x, wfrag, (float*)d_out);
}